// Round 15
// baseline (429.339 us; speedup 1.0000x reference)
//
#include <hip/hip_runtime.h>
#include <cmath>

// CXLoss MFMA pipeline, revision 15: R14's fragment-tiled direct-load sweep,
// occupancy doubled (NQ 4->8, grid 1024, __launch_bounds__(256,4) — legal
// since R14 compiled to exactly 128 VGPRs). Single-lever experiment:
// latency-bound at 2 waves/SIMD vs L2-BW-bound (~10 TB/s observed).

#define NB 4
#define CC 256
#define HW 4096
#define NQ 8   // loop-dim split per sweep (partials combined later)

static constexpr float kEPS = 1e-8f;
static constexpr float kSIG = 0.1f + 1e-8f;

typedef __attribute__((ext_vector_type(8)))  short short8;
typedef __attribute__((ext_vector_type(16))) float f32x16;

// workspace layout (float units)
enum {
  OFF_MEAN = 0,                      // 256 channel means
  OFF_BETA = 256,                    // NB*HW beta
  OFF_AG   = OFF_BETA + NB*HW,       // NB*HW alpha -> gamma
  OFF_CMAX = OFF_AG   + NB*HW,       // NQ*NB*HW colmax partials
  OFF_WSUM = OFF_CMAX + NQ*NB*HW,    // NQ*NB*HW Wsum partials
  OFF_MAXV = OFF_WSUM + NQ*NB*HW,    // NQ*NB*HW maxv partials
  OFF_GT   = OFF_MAXV + NQ*NB*HW,    // NB*HW*CC bf16 (ushort), tiled
  OFF_GI   = OFF_GT + NB*HW*CC/2,
  WS_FLOATS_FULL = OFF_GI + NB*HW*CC/2
};

__device__ __forceinline__ ushort cvt_bf16(float x) {
  unsigned u = __float_as_uint(x);
  unsigned r = (u + 0x7fffu + ((u >> 16) & 1u)) >> 16;  // round-nearest-even
  return (ushort)r;
}

__device__ __forceinline__ float blockSum256(float v) {
  __shared__ float sh[4];
  const int lane = threadIdx.x & 63, wv = threadIdx.x >> 6;
  #pragma unroll
  for (int o = 32; o > 0; o >>= 1) v += __shfl_down(v, o, 64);
  __syncthreads();
  if (lane == 0) sh[wv] = v;
  __syncthreads();
  return sh[0] + sh[1] + sh[2] + sh[3];
}

// K1: per-channel mean of featureT over (n,h,w). grid=256
__global__ __launch_bounds__(256) void k_mean6(const float* __restrict__ fT,
                                               float* __restrict__ ws) {
  const int c = blockIdx.x, t = threadIdx.x;
  float s = 0.f;
  for (int n = 0; n < NB; ++n) {
    const float* p = fT + (size_t)(n*CC + c)*HW;
    #pragma unroll
    for (int k = 0; k < 16; ++k) s += p[k*256 + t];
  }
  const float tot = blockSum256(s);
  if (t == 0) ws[OFF_MEAN + c] = tot * (1.0f/16384.0f);
}

// K2: fused normalize (mean-center, channel-L2) + write bf16 in fragment-tile
// order. Block = one tensor x one batch x one 32-pixel tile (r32), all 256 c.
// grid = 2 * NB * 128 = 1024 blocks of 256 threads.
// Tile layout: offset_ushort(n, r32, kc) = ((n*128 + r32)*16 + kc)*512 + l*8
//   holds X[n][p = r32*32 + (l&31)][c = kc*16 + (l>>5)*8 + j], j<8.
__global__ __launch_bounds__(256) void k_prep6(const float* __restrict__ fT,
                                               const float* __restrict__ fI,
                                               float* __restrict__ ws) {
  __shared__ float stage[32][257];   // [p_local][c], +1 pad
  __shared__ float prt[8][32];
  __shared__ float sinv[32];
  const int t = threadIdx.x, l = t & 63;
  int bid = blockIdx.x;
  const int tensor = (bid >= 512); bid &= 511;
  const int n   = bid >> 7;
  const int r32 = bid & 127;
  const int p0  = r32 * 32;

  const float* __restrict__ src = tensor ? fI : fT;
  ushort* __restrict__ dst = (ushort*)(ws + (tensor ? OFF_GI : OFF_GT));
  const float* __restrict__ mean = ws + OFF_MEAN;

  const int pl = t & 31, cg = t >> 5;          // 8 c-groups x 32 pixels
  float acc = 0.f;
  #pragma unroll
  for (int i = 0; i < 32; ++i) {
    const int c = cg*32 + i;
    const float v = src[((size_t)(n*CC + c))*HW + p0 + pl] - mean[c];
    stage[pl][c] = v;
    acc += v*v;
  }
  prt[cg][pl] = acc;
  __syncthreads();
  if (t < 32) {
    float s = 0.f;
    #pragma unroll
    for (int g = 0; g < 8; ++g) s += prt[g][t];
    sinv[t] = 1.0f/(sqrtf(s) + kEPS);
  }
  __syncthreads();

  // swizzled write: wave w handles kc in [w*4, w*4+4); 1KB tile per wave-store
  const int w = t >> 6, lhi = l >> 5, m = l & 31;
  const float iv = sinv[m];
  #pragma unroll
  for (int i = 0; i < 4; ++i) {
    const int kc = w*4 + i;
    const int cb = kc*16 + lhi*8;
    short8 o;
    #pragma unroll
    for (int j = 0; j < 8; ++j)
      ((ushort*)&o)[j] = cvt_bf16(stage[m][cb + j] * iv);
    *(short8*)(dst + (((size_t)(n*128 + r32)*16 + kc) << 9) + l*8) = o;
  }
}

// ---------------- MFMA sweep: direct-fragment loads, no K-loop barriers ---
// s[m][n] = sum_c gA[m][c]*gB[n][c]  (m = loop dim, n = resident dim)
// mode 0: colmax_q = max_m s ; mode 1: Wsum_q = sum_m exp(a_q + b_q s)
// mode 2: maxv_p = max_m (g_m + b_m s)
// grid = NB*32strips*NQ = 1024 blocks, 256 threads, 4 blocks/CU.
// Same-XCD blocks share h (b&7 == XCD id pattern) -> shared 512-row A-chunk
// (~1MB for all 4 n) fits the per-XCD 4MB L2.
__global__ __launch_bounds__(256, 4) void k_sweep_mfma6(
    const ushort* __restrict__ gA, const ushort* __restrict__ gB,
    float* __restrict__ ws, const int mode)
{
  __shared__ float red[2][128];
  __shared__ float gall[512], ball[512];  // mode-2 row params, whole strip

  const int t = threadIdx.x;
  const int w = t >> 6, l = t & 63;
  const int wm = w >> 1, wn = w & 1;
  const int ln31 = l & 31, lhi = l >> 5;

  const int b = blockIdx.x;
  const int h = b & 7, sid = b >> 3;
  const int n = sid >> 5;
  const int col0 = (sid & 31) * 128;
  const int loop0 = h * 512;              // 512-row strip = 16 r32 tiles

  // ---- B fragments: 32 coalesced 16B/lane loads, register-resident ----
  const int RB = (col0 >> 5) + wn*2;
  short8 breg[16][2];
  #pragma unroll
  for (int kc = 0; kc < 16; ++kc)
    #pragma unroll
    for (int in = 0; in < 2; ++in)
      breg[kc][in] = *(const short8*)(gB +
          (((size_t)(n*128 + RB + in)*16 + kc) << 9) + l*8);

  if (mode == 2) {
    #pragma unroll
    for (int i = 0; i < 2; ++i) {
      gall[i*256 + t] = ws[OFF_AG   + n*HW + loop0 + i*256 + t];
      ball[i*256 + t] = ws[OFF_BETA + n*HW + loop0 + i*256 + t];
    }
  }
  float aq[2], bq[2];   // mode-1 params per resident column
  if (mode == 1) {
    #pragma unroll
    for (int in = 0; in < 2; ++in) {
      const int q = col0 + wn*64 + in*32 + ln31;
      aq[in] = ws[OFF_AG   + n*HW + q];
      bq[in] = ws[OFF_BETA + n*HW + q];
    }
  }
  __syncthreads();   // gall/ball visible (only barrier before the end)

  float runl[2];
  runl[0] = runl[1] = (mode == 1) ? 0.0f : -3.0e38f;

  for (int tile = 0; tile < 4; ++tile) {
    // wave wm covers r32 tiles RA, RA+1; 4 waves cover 128 rows per iter
    const int RA = h*16 + tile*4 + wm*2;
    const ushort* __restrict__ pa =
        gA + (((size_t)(n*128 + RA)*16) << 9) + l*8;

    f32x16 acc[2][2];
    #pragma unroll
    for (int im = 0; im < 2; ++im)
      #pragma unroll
      for (int in = 0; in < 2; ++in)
        #pragma unroll
        for (int e = 0; e < 16; ++e) acc[im][in][e] = 0.f;

    // 32 independent coalesced loads + 64 MFMAs, no barriers: compiler
    // interleaves with partial vmcnt waits (AITER-style).
    #pragma unroll
    for (int kc = 0; kc < 16; ++kc) {
      const short8 a0 = *(const short8*)(pa + kc*512);
      const short8 a1 = *(const short8*)(pa + (16 + kc)*512);
      acc[0][0] = __builtin_amdgcn_mfma_f32_32x32x16_bf16(a0, breg[kc][0], acc[0][0], 0, 0, 0);
      acc[0][1] = __builtin_amdgcn_mfma_f32_32x32x16_bf16(a0, breg[kc][1], acc[0][1], 0, 0, 0);
      acc[1][0] = __builtin_amdgcn_mfma_f32_32x32x16_bf16(a1, breg[kc][0], acc[1][0], 0, 0, 0);
      acc[1][1] = __builtin_amdgcn_mfma_f32_32x32x16_bf16(a1, breg[kc][1], acc[1][1], 0, 0, 0);
    }

    // per-lane transform + accumulate.
    // C/D map: col = lane&31, row = (reg&3) + 8*(reg>>2) + 4*(lane>>5)
    if (mode == 0) {
      #pragma unroll
      for (int in = 0; in < 2; ++in) {
        float m = runl[in];
        #pragma unroll
        for (int im = 0; im < 2; ++im)
          #pragma unroll
          for (int r = 0; r < 16; ++r) m = fmaxf(m, acc[im][in][r]);
        runl[in] = m;
      }
    } else if (mode == 1) {
      #pragma unroll
      for (int in = 0; in < 2; ++in) {
        float s = 0.f;
        #pragma unroll
        for (int im = 0; im < 2; ++im)
          #pragma unroll
          for (int r = 0; r < 16; ++r)
            s += __expf(fmaf(bq[in], acc[im][in][r], aq[in]));
        runl[in] += s;
      }
    } else {
      const int tb = tile*128 + wm*64 + 4*lhi;
      #pragma unroll
      for (int in = 0; in < 2; ++in) {
        float m = runl[in];
        #pragma unroll
        for (int im = 0; im < 2; ++im) {
          #pragma unroll
          for (int rg = 0; rg < 4; ++rg) {
            const int rb = tb + im*32 + 8*rg;
            const float4 g4 = *(const float4*)&gall[rb];
            const float4 b4 = *(const float4*)&ball[rb];
            m = fmaxf(m, fmaf(b4.x, acc[im][in][rg*4+0], g4.x));
            m = fmaxf(m, fmaf(b4.y, acc[im][in][rg*4+1], g4.y));
            m = fmaxf(m, fmaf(b4.z, acc[im][in][rg*4+2], g4.z));
            m = fmaxf(m, fmaf(b4.w, acc[im][in][rg*4+3], g4.w));
          }
        }
        runl[in] = m;
      }
    }
  }

  // ---- single cross-lane + cross-wave reduction at the end ----
  #pragma unroll
  for (int in = 0; in < 2; ++in) {
    const float o = __shfl_xor(runl[in], 32, 64);
    runl[in] = (mode == 1) ? (runl[in] + o) : fmaxf(runl[in], o);
  }
  if (l < 32) {
    red[wm][wn*64 +  0 + ln31] = runl[0];
    red[wm][wn*64 + 32 + ln31] = runl[1];
  }
  __syncthreads();
  if (t < 128) {
    const float rv = (mode == 1) ? (red[0][t] + red[1][t])
                                 : fmaxf(red[0][t], red[1][t]);
    const int base = (mode == 0) ? OFF_CMAX : ((mode == 1) ? OFF_WSUM : OFF_MAXV);
    ws[base + h*(NB*HW) + n*HW + col0 + t] = rv;
  }
}

// K4: combine colmax partials -> alpha,beta per (n,q). grid=64
__global__ __launch_bounds__(256) void k_params6(float* __restrict__ ws) {
  const int idx = blockIdx.x*256 + threadIdx.x;
  float cm = ws[OFF_CMAX + idx];
  #pragma unroll
  for (int h = 1; h < NQ; ++h) cm = fmaxf(cm, ws[OFF_CMAX + h*(NB*HW) + idx]);
  const float div   = 0.5f*(1.0f - cm);
  const float inv2d = 1.0f/(2.0f*(div + kEPS));
  ws[OFF_BETA + idx] = inv2d / kSIG;
  ws[OFF_AG   + idx] = (1.0f - inv2d) / kSIG;
}

// K5: gamma = alpha - log(Wsum + eps). grid=64
__global__ __launch_bounds__(256) void k_gamma6(float* __restrict__ ws) {
  const int idx = blockIdx.x*256 + threadIdx.x;
  float s = 0.f;
  #pragma unroll
  for (int h = 0; h < NQ; ++h) s += ws[OFF_WSUM + h*(NB*HW) + idx];
  ws[OFF_AG + idx] = ws[OFF_AG + idx] - logf(s + kEPS);
}

// K6: final loss reduction. one block.
__global__ __launch_bounds__(256) void k_final6(const float* __restrict__ ws,
                                                float* __restrict__ out) {
  const int t = threadIdx.x;
  float loss = 0.f;
  for (int n = 0; n < NB; ++n) {
    float s = 0.f;
    for (int k = 0; k < 16; ++k) {
      const int idx = n*HW + k*256 + t;
      float mv = ws[OFF_MAXV + idx];
      #pragma unroll
      for (int h = 1; h < NQ; ++h) mv = fmaxf(mv, ws[OFF_MAXV + h*(NB*HW) + idx]);
      s += __expf(mv);
    }
    const float tot = blockSum256(s);
    loss += -logf(tot*(1.0f/4096.0f) + kEPS);
  }
  if (t == 0) out[0] = loss*0.25f;
}

extern "C" void kernel_launch(void* const* d_in, const int* in_sizes, int n_in,
                              void* d_out, int out_size, void* d_ws, size_t ws_size,
                              hipStream_t stream) {
  const float* fT = (const float*)d_in[0];
  const float* fI = (const float*)d_in[1];
  float* out = (float*)d_out;
  float* ws  = (float*)d_ws;

  const size_t need_full = (size_t)WS_FLOATS_FULL * sizeof(float);
  if (ws_size < need_full) return;  // ws measured 256 MB (R2); guard only

  const ushort* GT = (const ushort*)(ws + OFF_GT);
  const ushort* GI = (const ushort*)(ws + OFF_GI);
  k_mean6      <<<256,  256, 0, stream>>>(fT, ws);
  k_prep6      <<<1024, 256, 0, stream>>>(fT, fI, ws);
  k_sweep_mfma6<<<1024, 256, 0, stream>>>(GT, GI, ws, 0);  // colmax
  k_params6    <<<64,   256, 0, stream>>>(ws);
  k_sweep_mfma6<<<1024, 256, 0, stream>>>(GT, GI, ws, 1);  // Wsum
  k_gamma6     <<<64,   256, 0, stream>>>(ws);
  k_sweep_mfma6<<<1024, 256, 0, stream>>>(GI, GT, ws, 2);  // maxv
  k_final6     <<<1,    256, 0, stream>>>(ws, out);
}

// Round 16
// 243.117 us; speedup vs baseline: 1.7660x; 1.7660x over previous
//
#include <hip/hip_runtime.h>
#include <cmath>

// CXLoss MFMA pipeline, revision 16: register-lean direct-fragment sweep.
// R15 post-mortem: bounds(256,4) + 192-reg tile (breg 128V + acc 64A) =>
// breg spilled (VGPR 64, FETCH 300MB). Fix: per-wave tile 32x32 ->
// breg[16] (64 V) + acc f32x16 (16 A) ~= 110 regs, fits 4 waves/SIMD.
// 4 waves share A rows (L1 broadcast), jointly cover 128 cols. NQ=8.

#define NB 4
#define CC 256
#define HW 4096
#define NQ 8   // loop-dim split per sweep (partials combined later)

static constexpr float kEPS = 1e-8f;
static constexpr float kSIG = 0.1f + 1e-8f;

typedef __attribute__((ext_vector_type(8)))  short short8;
typedef __attribute__((ext_vector_type(16))) float f32x16;

// workspace layout (float units)
enum {
  OFF_MEAN = 0,                      // 256 channel means
  OFF_BETA = 256,                    // NB*HW beta
  OFF_AG   = OFF_BETA + NB*HW,       // NB*HW alpha -> gamma
  OFF_CMAX = OFF_AG   + NB*HW,       // NQ*NB*HW colmax partials
  OFF_WSUM = OFF_CMAX + NQ*NB*HW,    // NQ*NB*HW Wsum partials
  OFF_MAXV = OFF_WSUM + NQ*NB*HW,    // NQ*NB*HW maxv partials
  OFF_GT   = OFF_MAXV + NQ*NB*HW,    // NB*HW*CC bf16 (ushort), tiled
  OFF_GI   = OFF_GT + NB*HW*CC/2,
  WS_FLOATS_FULL = OFF_GI + NB*HW*CC/2
};

__device__ __forceinline__ ushort cvt_bf16(float x) {
  unsigned u = __float_as_uint(x);
  unsigned r = (u + 0x7fffu + ((u >> 16) & 1u)) >> 16;  // round-nearest-even
  return (ushort)r;
}

__device__ __forceinline__ float blockSum256(float v) {
  __shared__ float sh[4];
  const int lane = threadIdx.x & 63, wv = threadIdx.x >> 6;
  #pragma unroll
  for (int o = 32; o > 0; o >>= 1) v += __shfl_down(v, o, 64);
  __syncthreads();
  if (lane == 0) sh[wv] = v;
  __syncthreads();
  return sh[0] + sh[1] + sh[2] + sh[3];
}

// K1: per-channel mean of featureT over (n,h,w). grid=256
__global__ __launch_bounds__(256) void k_mean7(const float* __restrict__ fT,
                                               float* __restrict__ ws) {
  const int c = blockIdx.x, t = threadIdx.x;
  float s = 0.f;
  for (int n = 0; n < NB; ++n) {
    const float* p = fT + (size_t)(n*CC + c)*HW;
    #pragma unroll
    for (int k = 0; k < 16; ++k) s += p[k*256 + t];
  }
  const float tot = blockSum256(s);
  if (t == 0) ws[OFF_MEAN + c] = tot * (1.0f/16384.0f);
}

// K2: fused normalize + fragment-tiled bf16 write (verified R14 layout):
// offset_ushort(n, r32, kc) = ((n*128 + r32)*16 + kc)*512 + l*8
//   holds X[n][p = r32*32 + (l&31)][c = kc*16 + (l>>5)*8 + j], j<8.
// grid = 2 * NB * 128 = 1024 blocks of 256 threads.
__global__ __launch_bounds__(256) void k_prep7(const float* __restrict__ fT,
                                               const float* __restrict__ fI,
                                               float* __restrict__ ws) {
  __shared__ float stage[32][257];   // [p_local][c], +1 pad
  __shared__ float prt[8][32];
  __shared__ float sinv[32];
  const int t = threadIdx.x, l = t & 63;
  int bid = blockIdx.x;
  const int tensor = (bid >= 512); bid &= 511;
  const int n   = bid >> 7;
  const int r32 = bid & 127;
  const int p0  = r32 * 32;

  const float* __restrict__ src = tensor ? fI : fT;
  ushort* __restrict__ dst = (ushort*)(ws + (tensor ? OFF_GI : OFF_GT));
  const float* __restrict__ mean = ws + OFF_MEAN;

  const int pl = t & 31, cg = t >> 5;          // 8 c-groups x 32 pixels
  float acc = 0.f;
  #pragma unroll
  for (int i = 0; i < 32; ++i) {
    const int c = cg*32 + i;
    const float v = src[((size_t)(n*CC + c))*HW + p0 + pl] - mean[c];
    stage[pl][c] = v;
    acc += v*v;
  }
  prt[cg][pl] = acc;
  __syncthreads();
  if (t < 32) {
    float s = 0.f;
    #pragma unroll
    for (int g = 0; g < 8; ++g) s += prt[g][t];
    sinv[t] = 1.0f/(sqrtf(s) + kEPS);
  }
  __syncthreads();

  const int w = t >> 6, lhi = l >> 5, m = l & 31;
  const float iv = sinv[m];
  #pragma unroll
  for (int i = 0; i < 4; ++i) {
    const int kc = w*4 + i;
    const int cb = kc*16 + lhi*8;
    short8 o;
    #pragma unroll
    for (int j = 0; j < 8; ++j)
      ((ushort*)&o)[j] = cvt_bf16(stage[m][cb + j] * iv);
    *(short8*)(dst + (((size_t)(n*128 + r32)*16 + kc) << 9) + l*8) = o;
  }
}

// ---------------- MFMA sweep: lean 32x32/wave, 4 waves/SIMD ---------------
// s[m][n] = sum_c gA[m][c]*gB[n][c]  (m = loop dim, n = resident dim)
// mode 0: colmax_q = max_m s ; mode 1: Wsum_q = sum_m exp(a_q + b_q s)
// mode 2: maxv_p = max_m (g_m + b_m s)
// grid = NB * 32strips * NQ = 1024 blocks, 256 threads, 4 blocks/CU.
__global__ __launch_bounds__(256, 4) void k_sweep_mfma7(
    const ushort* __restrict__ gA, const ushort* __restrict__ gB,
    float* __restrict__ ws, const int mode)
{
  __shared__ float red2[128];
  __shared__ float gall[512], ball[512];  // mode-2 row params, 512-row strip

  const int t = threadIdx.x;
  const int w = t >> 6, l = t & 63;
  const int ln31 = l & 31, lhi = l >> 5;

  const int b = blockIdx.x;
  const int h = b & 7, sid = b >> 3;
  const int n = sid >> 5;
  const int col0 = (sid & 31) * 128;
  const int loop0 = h * 512;              // 512-row strip = 16 r32 tiles

  // ---- B fragments: wave w owns col-tile RB; 16 coalesced 16B loads ----
  const int RB = (col0 >> 5) + w;
  short8 breg[16];
  #pragma unroll
  for (int kc = 0; kc < 16; ++kc)
    breg[kc] = *(const short8*)(gB +
        (((size_t)(n*128 + RB)*16 + kc) << 9) + l*8);

  if (mode == 2) {
    #pragma unroll
    for (int i = 0; i < 2; ++i) {
      gall[i*256 + t] = ws[OFF_AG   + n*HW + loop0 + i*256 + t];
      ball[i*256 + t] = ws[OFF_BETA + n*HW + loop0 + i*256 + t];
    }
  }
  float aq = 0.f, bq = 0.f;     // mode-1 params for this lane's column
  if (mode == 1) {
    const int q = col0 + w*32 + ln31;
    aq = ws[OFF_AG   + n*HW + q];
    bq = ws[OFF_BETA + n*HW + q];
  }
  __syncthreads();   // gall/ball visible (only barrier before the end)

  float runl = (mode == 1) ? 0.0f : -3.0e38f;

  const ushort* __restrict__ pa0 =
      gA + (((size_t)(n*128 + h*16)*16) << 9) + l*8;

  for (int iter = 0; iter < 16; ++iter) {
    // all 4 waves read the same 32-row A tile (L1 broadcast)
    const ushort* __restrict__ pa = pa0 + ((size_t)iter << 13);  // 16*512

    f32x16 acc;
    #pragma unroll
    for (int e = 0; e < 16; ++e) acc[e] = 0.f;

    // 16 coalesced loads + 16 MFMAs, no barriers; compiler interleaves
    // with partial vmcnt waits.
    #pragma unroll
    for (int kc = 0; kc < 16; ++kc) {
      const short8 a0 = *(const short8*)(pa + kc*512);
      acc = __builtin_amdgcn_mfma_f32_32x32x16_bf16(a0, breg[kc], acc, 0, 0, 0);
    }

    // per-lane transform + accumulate.
    // C/D map: col = lane&31, row = (reg&3) + 8*(reg>>2) + 4*(lane>>5)
    if (mode == 0) {
      float m = runl;
      #pragma unroll
      for (int r = 0; r < 16; ++r) m = fmaxf(m, acc[r]);
      runl = m;
    } else if (mode == 1) {
      float s = 0.f;
      #pragma unroll
      for (int r = 0; r < 16; ++r) s += __expf(fmaf(bq, acc[r], aq));
      runl += s;
    } else {
      const int tb = iter*32 + 4*lhi;
      float m = runl;
      #pragma unroll
      for (int rg = 0; rg < 4; ++rg) {
        const int rb = tb + 8*rg;
        const float4 g4 = *(const float4*)&gall[rb];
        const float4 b4 = *(const float4*)&ball[rb];
        m = fmaxf(m, fmaf(b4.x, acc[rg*4+0], g4.x));
        m = fmaxf(m, fmaf(b4.y, acc[rg*4+1], g4.y));
        m = fmaxf(m, fmaf(b4.z, acc[rg*4+2], g4.z));
        m = fmaxf(m, fmaf(b4.w, acc[rg*4+3], g4.w));
      }
      runl = m;
    }
  }

  // ---- single cross-lane + cross-wave reduction at the end ----
  {
    const float o = __shfl_xor(runl, 32, 64);
    runl = (mode == 1) ? (runl + o) : fmaxf(runl, o);
  }
  if (l < 32) red2[w*32 + ln31] = runl;
  __syncthreads();
  if (t < 128) {
    const int base = (mode == 0) ? OFF_CMAX : ((mode == 1) ? OFF_WSUM : OFF_MAXV);
    ws[base + h*(NB*HW) + n*HW + col0 + t] = red2[t];
  }
}

// K4: combine colmax partials -> alpha,beta per (n,q). grid=64
__global__ __launch_bounds__(256) void k_params7(float* __restrict__ ws) {
  const int idx = blockIdx.x*256 + threadIdx.x;
  float cm = ws[OFF_CMAX + idx];
  #pragma unroll
  for (int h = 1; h < NQ; ++h) cm = fmaxf(cm, ws[OFF_CMAX + h*(NB*HW) + idx]);
  const float div   = 0.5f*(1.0f - cm);
  const float inv2d = 1.0f/(2.0f*(div + kEPS));
  ws[OFF_BETA + idx] = inv2d / kSIG;
  ws[OFF_AG   + idx] = (1.0f - inv2d) / kSIG;
}

// K5: gamma = alpha - log(Wsum + eps). grid=64
__global__ __launch_bounds__(256) void k_gamma7(float* __restrict__ ws) {
  const int idx = blockIdx.x*256 + threadIdx.x;
  float s = 0.f;
  #pragma unroll
  for (int h = 0; h < NQ; ++h) s += ws[OFF_WSUM + h*(NB*HW) + idx];
  ws[OFF_AG + idx] = ws[OFF_AG + idx] - logf(s + kEPS);
}

// K6: final loss reduction. one block.
__global__ __launch_bounds__(256) void k_final7(const float* __restrict__ ws,
                                                float* __restrict__ out) {
  const int t = threadIdx.x;
  float loss = 0.f;
  for (int n = 0; n < NB; ++n) {
    float s = 0.f;
    for (int k = 0; k < 16; ++k) {
      const int idx = n*HW + k*256 + t;
      float mv = ws[OFF_MAXV + idx];
      #pragma unroll
      for (int h = 1; h < NQ; ++h) mv = fmaxf(mv, ws[OFF_MAXV + h*(NB*HW) + idx]);
      s += __expf(mv);
    }
    const float tot = blockSum256(s);
    loss += -logf(tot*(1.0f/4096.0f) + kEPS);
  }
  if (t == 0) out[0] = loss*0.25f;
}

extern "C" void kernel_launch(void* const* d_in, const int* in_sizes, int n_in,
                              void* d_out, int out_size, void* d_ws, size_t ws_size,
                              hipStream_t stream) {
  const float* fT = (const float*)d_in[0];
  const float* fI = (const float*)d_in[1];
  float* out = (float*)d_out;
  float* ws  = (float*)d_ws;

  const size_t need_full = (size_t)WS_FLOATS_FULL * sizeof(float);
  if (ws_size < need_full) return;  // ws measured 256 MB (R2); guard only

  const ushort* GT = (const ushort*)(ws + OFF_GT);
  const ushort* GI = (const ushort*)(ws + OFF_GI);
  k_mean7      <<<256,  256, 0, stream>>>(fT, ws);
  k_prep7      <<<1024, 256, 0, stream>>>(fT, fI, ws);
  k_sweep_mfma7<<<1024, 256, 0, stream>>>(GT, GI, ws, 0);  // colmax
  k_params7    <<<64,   256, 0, stream>>>(ws);
  k_sweep_mfma7<<<1024, 256, 0, stream>>>(GT, GI, ws, 1);  // Wsum
  k_gamma7     <<<64,   256, 0, stream>>>(ws);
  k_sweep_mfma7<<<1024, 256, 0, stream>>>(GI, GT, ws, 2);  // maxv
  k_final7     <<<1,    256, 0, stream>>>(ws, out);
}

// Round 17
// 213.876 us; speedup vs baseline: 2.0074x; 1.1367x over previous
//
#include <hip/hip_runtime.h>
#include <cmath>

// CXLoss MFMA pipeline, revision 17:
// - A-tiles staged once per block into double-buffered LDS (removes the 4x
//   per-wave VMEM redundancy that capped R16 at ~27us+ of L1 return traffic),
//   ds_read_b128 fragments, one barrier/iter, prefetch-after-barrier.
// - 4 waves/SIMD (breg 64V + pf 16V + acc 16A ~= 120 regs).
// - k_params fused into sweep mode-1 prologue, k_gamma into mode-2 prologue
//   (local recompute from partials; 8 -> 6 dispatches).

#define NB 4
#define CC 256
#define HW 4096
#define NQ 8   // loop-dim split per sweep (partials combined later)

static constexpr float kEPS = 1e-8f;
static constexpr float kSIG = 0.1f + 1e-8f;

typedef __attribute__((ext_vector_type(8)))  short short8;
typedef __attribute__((ext_vector_type(16))) float f32x16;

// workspace layout (float units)
enum {
  OFF_MEAN = 0,                      // 256 channel means
  OFF_CMAX = 256,                    // NQ*NB*HW colmax partials
  OFF_WSUM = OFF_CMAX + NQ*NB*HW,    // NQ*NB*HW Wsum partials
  OFF_MAXV = OFF_WSUM + NQ*NB*HW,    // NQ*NB*HW maxv partials
  OFF_GT   = OFF_MAXV + NQ*NB*HW,    // NB*HW*CC bf16 (ushort), tiled
  OFF_GI   = OFF_GT + NB*HW*CC/2,
  WS_FLOATS_FULL = OFF_GI + NB*HW*CC/2
};

__device__ __forceinline__ ushort cvt_bf16(float x) {
  unsigned u = __float_as_uint(x);
  unsigned r = (u + 0x7fffu + ((u >> 16) & 1u)) >> 16;  // round-nearest-even
  return (ushort)r;
}

__device__ __forceinline__ float blockSum256(float v) {
  __shared__ float sh[4];
  const int lane = threadIdx.x & 63, wv = threadIdx.x >> 6;
  #pragma unroll
  for (int o = 32; o > 0; o >>= 1) v += __shfl_down(v, o, 64);
  __syncthreads();
  if (lane == 0) sh[wv] = v;
  __syncthreads();
  return sh[0] + sh[1] + sh[2] + sh[3];
}

// K1: per-channel mean of featureT over (n,h,w). grid=256
__global__ __launch_bounds__(256) void k_mean8(const float* __restrict__ fT,
                                               float* __restrict__ ws) {
  const int c = blockIdx.x, t = threadIdx.x;
  float s = 0.f;
  for (int n = 0; n < NB; ++n) {
    const float* p = fT + (size_t)(n*CC + c)*HW;
    #pragma unroll
    for (int k = 0; k < 16; ++k) s += p[k*256 + t];
  }
  const float tot = blockSum256(s);
  if (t == 0) ws[OFF_MEAN + c] = tot * (1.0f/16384.0f);
}

// K2: fused normalize + fragment-tiled bf16 write (verified R14 layout):
// offset_ushort(n, r32, kc) = ((n*128 + r32)*16 + kc)*512 + l*8
//   holds X[n][p = r32*32 + (l&31)][c = kc*16 + (l>>5)*8 + j], j<8.
// grid = 2 * NB * 128 = 1024 blocks of 256 threads.
__global__ __launch_bounds__(256) void k_prep8(const float* __restrict__ fT,
                                               const float* __restrict__ fI,
                                               float* __restrict__ ws) {
  __shared__ float stage[32][257];   // [p_local][c], +1 pad
  __shared__ float prt[8][32];
  __shared__ float sinv[32];
  const int t = threadIdx.x, l = t & 63;
  int bid = blockIdx.x;
  const int tensor = (bid >= 512); bid &= 511;
  const int n   = bid >> 7;
  const int r32 = bid & 127;
  const int p0  = r32 * 32;

  const float* __restrict__ src = tensor ? fI : fT;
  ushort* __restrict__ dst = (ushort*)(ws + (tensor ? OFF_GI : OFF_GT));
  const float* __restrict__ mean = ws + OFF_MEAN;

  const int pl = t & 31, cg = t >> 5;          // 8 c-groups x 32 pixels
  float acc = 0.f;
  #pragma unroll
  for (int i = 0; i < 32; ++i) {
    const int c = cg*32 + i;
    const float v = src[((size_t)(n*CC + c))*HW + p0 + pl] - mean[c];
    stage[pl][c] = v;
    acc += v*v;
  }
  prt[cg][pl] = acc;
  __syncthreads();
  if (t < 32) {
    float s = 0.f;
    #pragma unroll
    for (int g = 0; g < 8; ++g) s += prt[g][t];
    sinv[t] = 1.0f/(sqrtf(s) + kEPS);
  }
  __syncthreads();

  const int w = t >> 6, lhi = l >> 5, m = l & 31;
  const float iv = sinv[m];
  #pragma unroll
  for (int i = 0; i < 4; ++i) {
    const int kc = w*4 + i;
    const int cb = kc*16 + lhi*8;
    short8 o;
    #pragma unroll
    for (int j = 0; j < 8; ++j)
      ((ushort*)&o)[j] = cvt_bf16(stage[m][cb + j] * iv);
    *(short8*)(dst + (((size_t)(n*128 + r32)*16 + kc) << 9) + l*8) = o;
  }
}

// ---------------- MFMA sweep: LDS-shared A, 4 waves/SIMD ------------------
// s[m][n] = sum_c gA[m][c]*gB[n][c]  (m = loop dim, n = resident dim)
// mode 0: colmax_q = max_m s
// mode 1: Wsum_q = sum_m exp(a_q + b_q s)   [a,b recomputed from CMAX]
// mode 2: maxv_p = max_m (g_m + b_m s)      [g,b recomputed from CMAX+WSUM]
// grid = NB * 32strips * NQ = 1024 blocks, 256 threads, 4 blocks/CU.
__global__ __launch_bounds__(256, 4) void k_sweep_mfma8(
    const ushort* __restrict__ gA, const ushort* __restrict__ gB,
    float* __restrict__ ws, const int mode)
{
  __shared__ ushort Ab[2][8192];     // double-buffered 32-row A tile (16KB)
  __shared__ float red2[128];
  __shared__ float gall[512], ball[512];  // mode-2 row params, 512-row strip

  const int t = threadIdx.x;
  const int w = t >> 6, l = t & 63;
  const int ln31 = l & 31, lhi = l >> 5;

  const int b = blockIdx.x;
  const int h = b & 7, sid = b >> 3;
  const int n = sid >> 5;
  const int col0 = (sid & 31) * 128;
  const int loop0 = h * 512;              // 512-row strip = 16 r32 tiles

  // A strip base (ushort idx): tiles h*16 .. h*16+15, 8192 ushorts each
  const ushort* __restrict__ gAn = gA + (size_t)(n*128 + h*16)*8192;

  // ---- prologue staging: tile0 -> Ab[0]; tile1 -> pf ----
  short8 pf[4];
  #pragma unroll
  for (int i = 0; i < 4; ++i)
    pf[i] = *(const short8*)(gAn + (size_t)(i*256 + t)*8);
  #pragma unroll
  for (int i = 0; i < 4; ++i)
    *(short8*)&Ab[0][(i*256 + t)*8] = pf[i];
  #pragma unroll
  for (int i = 0; i < 4; ++i)
    pf[i] = *(const short8*)(gAn + 8192 + (size_t)(i*256 + t)*8);

  // ---- B fragments: wave w owns col-tile RB; 16 coalesced 16B loads ----
  const int RB = (col0 >> 5) + w;
  short8 breg[16];
  #pragma unroll
  for (int kc = 0; kc < 16; ++kc)
    breg[kc] = *(const short8*)(gB +
        (((size_t)(n*128 + RB)*16 + kc) << 9) + l*8);

  // ---- fused parameter prologues (replace k_params / k_gamma) ----
  float aq = 0.f, bq = 0.f;     // mode-1 params for this lane's column
  if (mode == 1) {
    const int q = col0 + w*32 + ln31;
    float cm = -3.0e38f;
    #pragma unroll
    for (int hh = 0; hh < NQ; ++hh)
      cm = fmaxf(cm, ws[OFF_CMAX + hh*(NB*HW) + n*HW + q]);
    const float div   = 0.5f*(1.0f - cm);
    const float inv2d = 1.0f/(2.0f*(div + kEPS));
    bq = inv2d / kSIG;
    aq = (1.0f - inv2d) / kSIG;
  }
  if (mode == 2) {
    #pragma unroll
    for (int i = 0; i < 2; ++i) {
      const int r = i*256 + t;          // 0..511
      const int q = loop0 + r;
      float cm = -3.0e38f, sw = 0.f;
      #pragma unroll
      for (int hh = 0; hh < NQ; ++hh) {
        cm = fmaxf(cm, ws[OFF_CMAX + hh*(NB*HW) + n*HW + q]);
        sw += ws[OFF_WSUM + hh*(NB*HW) + n*HW + q];
      }
      const float div   = 0.5f*(1.0f - cm);
      const float inv2d = 1.0f/(2.0f*(div + kEPS));
      const float beta  = inv2d / kSIG;
      const float alpha = (1.0f - inv2d) / kSIG;
      ball[r] = beta;
      gall[r] = alpha - logf(sw + kEPS);
    }
  }

  float runl = (mode == 1) ? 0.0f : -3.0e38f;

  for (int iter = 0; iter < 16; ++iter) {
    const int p = iter & 1;
    __syncthreads();   // Ab[p] stores visible; prior reads of Ab[p^1] done
    if (iter + 1 < 16) {
      #pragma unroll
      for (int i = 0; i < 4; ++i)
        *(short8*)&Ab[p^1][(i*256 + t)*8] = pf[i];
      if (iter + 2 < 16) {
        const ushort* __restrict__ src = gAn + (size_t)(iter + 2)*8192;
        #pragma unroll
        for (int i = 0; i < 4; ++i)
          pf[i] = *(const short8*)(src + (size_t)(i*256 + t)*8);
      }
    }

    f32x16 acc;
    #pragma unroll
    for (int e = 0; e < 16; ++e) acc[e] = 0.f;

    // 16 conflict-free ds_read_b128 + 16 MFMAs (all 4 waves share the tile)
    #pragma unroll
    for (int kc = 0; kc < 16; ++kc) {
      const short8 a0 = *(const short8*)&Ab[p][kc*512 + l*8];
      acc = __builtin_amdgcn_mfma_f32_32x32x16_bf16(a0, breg[kc], acc, 0, 0, 0);
    }

    // per-lane transform + accumulate.
    // C/D map: col = lane&31, row = (reg&3) + 8*(reg>>2) + 4*(lane>>5)
    if (mode == 0) {
      float m = runl;
      #pragma unroll
      for (int r = 0; r < 16; ++r) m = fmaxf(m, acc[r]);
      runl = m;
    } else if (mode == 1) {
      float s = 0.f;
      #pragma unroll
      for (int r = 0; r < 16; ++r) s += __expf(fmaf(bq, acc[r], aq));
      runl += s;
    } else {
      const int tb = iter*32 + 4*lhi;
      float m = runl;
      #pragma unroll
      for (int rg = 0; rg < 4; ++rg) {
        const int rb = tb + 8*rg;
        const float4 g4 = *(const float4*)&gall[rb];
        const float4 b4 = *(const float4*)&ball[rb];
        m = fmaxf(m, fmaf(b4.x, acc[rg*4+0], g4.x));
        m = fmaxf(m, fmaf(b4.y, acc[rg*4+1], g4.y));
        m = fmaxf(m, fmaf(b4.z, acc[rg*4+2], g4.z));
        m = fmaxf(m, fmaf(b4.w, acc[rg*4+3], g4.w));
      }
      runl = m;
    }
  }

  // ---- single cross-lane + cross-wave reduction at the end ----
  {
    const float o = __shfl_xor(runl, 32, 64);
    runl = (mode == 1) ? (runl + o) : fmaxf(runl, o);
  }
  if (l < 32) red2[w*32 + ln31] = runl;
  __syncthreads();
  if (t < 128) {
    const int base = (mode == 0) ? OFF_CMAX : ((mode == 1) ? OFF_WSUM : OFF_MAXV);
    ws[base + h*(NB*HW) + n*HW + col0 + t] = red2[t];
  }
}

// K6: final loss reduction. one block.
__global__ __launch_bounds__(256) void k_final8(const float* __restrict__ ws,
                                                float* __restrict__ out) {
  const int t = threadIdx.x;
  float loss = 0.f;
  for (int n = 0; n < NB; ++n) {
    float s = 0.f;
    for (int k = 0; k < 16; ++k) {
      const int idx = n*HW + k*256 + t;
      float mv = ws[OFF_MAXV + idx];
      #pragma unroll
      for (int h = 1; h < NQ; ++h) mv = fmaxf(mv, ws[OFF_MAXV + h*(NB*HW) + idx]);
      s += __expf(mv);
    }
    const float tot = blockSum256(s);
    loss += -logf(tot*(1.0f/4096.0f) + kEPS);
  }
  if (t == 0) out[0] = loss*0.25f;
}

extern "C" void kernel_launch(void* const* d_in, const int* in_sizes, int n_in,
                              void* d_out, int out_size, void* d_ws, size_t ws_size,
                              hipStream_t stream) {
  const float* fT = (const float*)d_in[0];
  const float* fI = (const float*)d_in[1];
  float* out = (float*)d_out;
  float* ws  = (float*)d_ws;

  const size_t need_full = (size_t)WS_FLOATS_FULL * sizeof(float);
  if (ws_size < need_full) return;  // ws measured 256 MB (R2); guard only

  const ushort* GT = (const ushort*)(ws + OFF_GT);
  const ushort* GI = (const ushort*)(ws + OFF_GI);
  k_mean8      <<<256,  256, 0, stream>>>(fT, ws);
  k_prep8      <<<1024, 256, 0, stream>>>(fT, fI, ws);
  k_sweep_mfma8<<<1024, 256, 0, stream>>>(GT, GI, ws, 0);  // colmax
  k_sweep_mfma8<<<1024, 256, 0, stream>>>(GT, GI, ws, 1);  // Wsum (params fused)
  k_sweep_mfma8<<<1024, 256, 0, stream>>>(GI, GT, ws, 2);  // maxv (gamma fused)
  k_final8     <<<1,    256, 0, stream>>>(ws, out);
}

// Round 18
// 205.095 us; speedup vs baseline: 2.0934x; 1.0428x over previous
//
#include <hip/hip_runtime.h>
#include <cmath>

// CXLoss pipeline, revision 18: materialize S (bf16, 134MB in ws) — GEMM runs
// ONCE. k_gemm = R17's verified mode-0 sweep + bf16-rounded S store (colmax
// taken over the rounded values => bit-consistent with stored S). Then two
// memory-bound passes over S (LLC-resident) replace the other two GEMMs.

#define NB 4
#define CC 256
#define HW 4096
#define NQ0 8    // gemm loop-split (CMAX partials)
#define NP1 32   // pass1 p-chunks (WSUM partials)

static constexpr float kEPS = 1e-8f;
static constexpr float kSIG = 0.1f + 1e-8f;

typedef __attribute__((ext_vector_type(8)))  short short8;
typedef __attribute__((ext_vector_type(16))) float f32x16;

// workspace layout (float units)
enum {
  OFF_MEAN = 0,                        // 256 channel means
  OFF_CMAX = 256,                      // NQ0*NB*HW colmax partials
  OFF_WSUM = OFF_CMAX + NQ0*NB*HW,     // NP1*NB*HW Wsum partials
  OFF_MAXV = OFF_WSUM + NP1*NB*HW,     // NB*HW maxv (direct)
  OFF_GB   = OFF_MAXV + NB*HW,         // gamma[NB*HW], beta[NB*HW]
  OFF_GT   = OFF_GB + 2*NB*HW,         // NB*HW*CC bf16, fragment-tiled
  OFF_GI   = OFF_GT + NB*HW*CC/2,
  OFF_S    = OFF_GI + NB*HW*CC/2,      // NB*HW*HW bf16  (134 MB)
  WS_FLOATS_FULL = OFF_S + NB*HW*HW/2
};

__device__ __forceinline__ ushort cvt_bf16(float x) {
  unsigned u = __float_as_uint(x);
  unsigned r = (u + 0x7fffu + ((u >> 16) & 1u)) >> 16;  // round-nearest-even
  return (ushort)r;
}
__device__ __forceinline__ float bf2f(ushort u) {
  return __uint_as_float((unsigned)u << 16);
}

__device__ __forceinline__ float blockSum256(float v) {
  __shared__ float sh[4];
  const int lane = threadIdx.x & 63, wv = threadIdx.x >> 6;
  #pragma unroll
  for (int o = 32; o > 0; o >>= 1) v += __shfl_down(v, o, 64);
  __syncthreads();
  if (lane == 0) sh[wv] = v;
  __syncthreads();
  return sh[0] + sh[1] + sh[2] + sh[3];
}

// K1: per-channel mean of featureT. grid=256
__global__ __launch_bounds__(256) void k_mean9(const float* __restrict__ fT,
                                               float* __restrict__ ws) {
  const int c = blockIdx.x, t = threadIdx.x;
  float s = 0.f;
  for (int n = 0; n < NB; ++n) {
    const float* p = fT + (size_t)(n*CC + c)*HW;
    #pragma unroll
    for (int k = 0; k < 16; ++k) s += p[k*256 + t];
  }
  const float tot = blockSum256(s);
  if (t == 0) ws[OFF_MEAN + c] = tot * (1.0f/16384.0f);
}

// K2: fused normalize + fragment-tiled bf16 write (verified R14 layout):
// offset_ushort(n, r32, kc) = ((n*128 + r32)*16 + kc)*512 + l*8
//   holds X[n][p = r32*32 + (l&31)][c = kc*16 + (l>>5)*8 + j], j<8.
// grid = 2 * NB * 128 = 1024 blocks.
__global__ __launch_bounds__(256) void k_prep9(const float* __restrict__ fT,
                                               const float* __restrict__ fI,
                                               float* __restrict__ ws) {
  __shared__ float stage[32][257];
  __shared__ float prt[8][32];
  __shared__ float sinv[32];
  const int t = threadIdx.x, l = t & 63;
  int bid = blockIdx.x;
  const int tensor = (bid >= 512); bid &= 511;
  const int n   = bid >> 7;
  const int r32 = bid & 127;
  const int p0  = r32 * 32;

  const float* __restrict__ src = tensor ? fI : fT;
  ushort* __restrict__ dst = (ushort*)(ws + (tensor ? OFF_GI : OFF_GT));
  const float* __restrict__ mean = ws + OFF_MEAN;

  const int pl = t & 31, cg = t >> 5;
  float acc = 0.f;
  #pragma unroll
  for (int i = 0; i < 32; ++i) {
    const int c = cg*32 + i;
    const float v = src[((size_t)(n*CC + c))*HW + p0 + pl] - mean[c];
    stage[pl][c] = v;
    acc += v*v;
  }
  prt[cg][pl] = acc;
  __syncthreads();
  if (t < 32) {
    float s = 0.f;
    #pragma unroll
    for (int g = 0; g < 8; ++g) s += prt[g][t];
    sinv[t] = 1.0f/(sqrtf(s) + kEPS);
  }
  __syncthreads();

  const int w = t >> 6, lhi = l >> 5, m = l & 31;
  const float iv = sinv[m];
  #pragma unroll
  for (int i = 0; i < 4; ++i) {
    const int kc = w*4 + i;
    const int cb = kc*16 + lhi*8;
    short8 o;
    #pragma unroll
    for (int j = 0; j < 8; ++j)
      ((ushort*)&o)[j] = cvt_bf16(stage[m][cb + j] * iv);
    *(short8*)(dst + (((size_t)(n*128 + r32)*16 + kc) << 9) + l*8) = o;
  }
}

// K3: single GEMM sweep (R17 mode-0 structure) + bf16 S store + colmax.
// grid = NB*32strips*NQ0 = 1024 blocks, 4 blocks/CU.
__global__ __launch_bounds__(256, 4) void k_gemm9(
    const ushort* __restrict__ gA, const ushort* __restrict__ gB,
    float* __restrict__ ws)
{
  __shared__ ushort Ab[2][8192];     // double-buffered 32-row A tile (16KB)
  __shared__ float red2[128];

  const int t = threadIdx.x;
  const int w = t >> 6, l = t & 63;
  const int ln31 = l & 31, lhi = l >> 5;

  const int b = blockIdx.x;
  const int h = b & 7, sid = b >> 3;
  const int n = sid >> 5;
  const int col0 = (sid & 31) * 128;

  const ushort* __restrict__ gAn = gA + (size_t)(n*128 + h*16)*8192;

  // prologue staging: tile0 -> Ab[0]; tile1 -> pf
  short8 pf[4];
  #pragma unroll
  for (int i = 0; i < 4; ++i)
    pf[i] = *(const short8*)(gAn + (size_t)(i*256 + t)*8);
  #pragma unroll
  for (int i = 0; i < 4; ++i)
    *(short8*)&Ab[0][(i*256 + t)*8] = pf[i];
  #pragma unroll
  for (int i = 0; i < 4; ++i)
    pf[i] = *(const short8*)(gAn + 8192 + (size_t)(i*256 + t)*8);

  // B fragments: wave w owns col-tile RB
  const int RB = (col0 >> 5) + w;
  short8 breg[16];
  #pragma unroll
  for (int kc = 0; kc < 16; ++kc)
    breg[kc] = *(const short8*)(gB +
        (((size_t)(n*128 + RB)*16 + kc) << 9) + l*8);

  const int qc = col0 + w*32 + ln31;
  ushort* __restrict__ Sq = (ushort*)(ws + OFF_S) + (size_t)n*HW*HW + qc;

  float runl = -3.0e38f;

  for (int iter = 0; iter < 16; ++iter) {
    const int p = iter & 1;
    __syncthreads();
    if (iter + 1 < 16) {
      #pragma unroll
      for (int i = 0; i < 4; ++i)
        *(short8*)&Ab[p^1][(i*256 + t)*8] = pf[i];
      if (iter + 2 < 16) {
        const ushort* __restrict__ src = gAn + (size_t)(iter + 2)*8192;
        #pragma unroll
        for (int i = 0; i < 4; ++i)
          pf[i] = *(const short8*)(src + (size_t)(i*256 + t)*8);
      }
    }

    f32x16 acc;
    #pragma unroll
    for (int e = 0; e < 16; ++e) acc[e] = 0.f;
    #pragma unroll
    for (int kc = 0; kc < 16; ++kc) {
      const short8 a0 = *(const short8*)&Ab[p][kc*512 + l*8];
      acc = __builtin_amdgcn_mfma_f32_32x32x16_bf16(a0, breg[kc], acc, 0, 0, 0);
    }

    // epilogue: round->store S, colmax over ROUNDED values (consistency).
    // C/D map: col = lane&31, row = (reg&3) + 8*(reg>>2) + 4*(lane>>5)
    const int pb = h*512 + iter*32 + 4*lhi;
    #pragma unroll
    for (int r = 0; r < 16; ++r) {
      const int prow = pb + (r & 3) + 8*(r >> 2);
      const ushort u = cvt_bf16(acc[r]);
      Sq[(size_t)prow * HW] = u;
      runl = fmaxf(runl, bf2f(u));
    }
  }

  {
    const float o = __shfl_xor(runl, 32, 64);
    runl = fmaxf(runl, o);
  }
  if (l < 32) red2[w*32 + ln31] = runl;
  __syncthreads();
  if (t < 128)
    ws[OFF_CMAX + h*(NB*HW) + n*HW + col0 + t] = red2[t];
}

// K4: pass1 — Wsum partials. block: (n, qblk of 512, pchunk of 128).
// grid = 4 * 8 * 32 = 1024. thread t owns q = qblk*512 + 2t (+0,+1).
__global__ __launch_bounds__(256) void k_pass1(float* __restrict__ ws) {
  const int t = threadIdx.x;
  const int b = blockIdx.x;
  const int pc = b & 31, rest = b >> 5;
  const int n = rest >> 3, qblk = rest & 7;
  const int q = qblk*512 + 2*t;

  float a0, b0, a1, b1;
  {
    float cm0 = -3.0e38f, cm1 = -3.0e38f;
    #pragma unroll
    for (int hh = 0; hh < NQ0; ++hh) {
      cm0 = fmaxf(cm0, ws[OFF_CMAX + hh*(NB*HW) + n*HW + q]);
      cm1 = fmaxf(cm1, ws[OFF_CMAX + hh*(NB*HW) + n*HW + q + 1]);
    }
    const float i0 = 1.0f/(2.0f*(0.5f*(1.0f - cm0) + kEPS));
    const float i1 = 1.0f/(2.0f*(0.5f*(1.0f - cm1) + kEPS));
    b0 = i0 / kSIG; a0 = (1.0f - i0) / kSIG;
    b1 = i1 / kSIG; a1 = (1.0f - i1) / kSIG;
  }

  const ushort* __restrict__ S =
      (const ushort*)(ws + OFF_S) + (size_t)n*HW*HW + q;
  float acc0 = 0.f, acc1 = 0.f;
  const int p0 = pc*128;
  #pragma unroll 8
  for (int i = 0; i < 128; ++i) {
    const ushort2 u = *(const ushort2*)(S + (size_t)(p0 + i)*HW);
    acc0 += __expf(fmaf(b0, bf2f(u.x), a0));
    acc1 += __expf(fmaf(b1, bf2f(u.y), a1));
  }
  float2 o; o.x = acc0; o.y = acc1;
  *(float2*)&ws[OFF_WSUM + pc*(NB*HW) + n*HW + q] = o;
}

// K5: gamma/beta arrays. grid = 64 (NB*HW/256).
__global__ __launch_bounds__(256) void k_gb9(float* __restrict__ ws) {
  const int idx = blockIdx.x*256 + threadIdx.x;   // n*HW + q
  float cm = -3.0e38f;
  #pragma unroll
  for (int hh = 0; hh < NQ0; ++hh)
    cm = fmaxf(cm, ws[OFF_CMAX + hh*(NB*HW) + idx]);
  const float inv2d = 1.0f/(2.0f*(0.5f*(1.0f - cm) + kEPS));
  const float beta  = inv2d / kSIG;
  const float alpha = (1.0f - inv2d) / kSIG;
  float sw = 0.f;
  #pragma unroll
  for (int pc = 0; pc < NP1; ++pc)
    sw += ws[OFF_WSUM + pc*(NB*HW) + idx];
  ws[OFF_GB + idx]         = alpha - logf(sw + kEPS);  // gamma
  ws[OFF_GB + NB*HW + idx] = beta;
}

// K6: pass2 — maxv[n][p] = max_q (gamma_q + beta_q * s[p][q]).
// grid = NB * 256 = 1024; block owns 16 p-rows; gamma/beta staged in LDS.
__global__ __launch_bounds__(256) void k_pass2(float* __restrict__ ws) {
  __shared__ float gq[4096], bq[4096];
  const int t = threadIdx.x, w = t >> 6, l = t & 63;
  const int b = blockIdx.x;
  const int n = b >> 8, pg = b & 255;

  const float* __restrict__ G  = ws + OFF_GB + n*HW;
  const float* __restrict__ Bq = ws + OFF_GB + NB*HW + n*HW;
  #pragma unroll
  for (int i = 0; i < 4; ++i) {
    *(float4*)&gq[(i*256 + t)*4] = *(const float4*)&G [(i*256 + t)*4];
    *(float4*)&bq[(i*256 + t)*4] = *(const float4*)&Bq[(i*256 + t)*4];
  }
  __syncthreads();

  const ushort* __restrict__ S =
      (const ushort*)(ws + OFF_S) + (size_t)n*HW*HW;
  #pragma unroll
  for (int r = 0; r < 4; ++r) {
    const int p = pg*16 + w*4 + r;
    const ushort* __restrict__ row = S + (size_t)p*HW;
    float m = -3.0e38f;
    #pragma unroll 4
    for (int it = 0; it < 32; ++it) {
      const int q = it*128 + 2*l;
      const ushort2 u = *(const ushort2*)(row + q);
      m = fmaxf(m, fmaf(bq[q],     bf2f(u.x), gq[q]));
      m = fmaxf(m, fmaf(bq[q + 1], bf2f(u.y), gq[q + 1]));
    }
    #pragma unroll
    for (int o = 32; o > 0; o >>= 1) m = fmaxf(m, __shfl_xor(m, o, 64));
    if (l == 0) ws[OFF_MAXV + n*HW + p] = m;
  }
}

// K7: final loss. one block.
__global__ __launch_bounds__(256) void k_final9(const float* __restrict__ ws,
                                                float* __restrict__ out) {
  const int t = threadIdx.x;
  float loss = 0.f;
  for (int n = 0; n < NB; ++n) {
    float s = 0.f;
    for (int k = 0; k < 16; ++k)
      s += __expf(ws[OFF_MAXV + n*HW + k*256 + t]);
    const float tot = blockSum256(s);
    loss += -logf(tot*(1.0f/4096.0f) + kEPS);
  }
  if (t == 0) out[0] = loss*0.25f;
}

extern "C" void kernel_launch(void* const* d_in, const int* in_sizes, int n_in,
                              void* d_out, int out_size, void* d_ws, size_t ws_size,
                              hipStream_t stream) {
  const float* fT = (const float*)d_in[0];
  const float* fI = (const float*)d_in[1];
  float* out = (float*)d_out;
  float* ws  = (float*)d_ws;

  const size_t need_full = (size_t)WS_FLOATS_FULL * sizeof(float);
  if (ws_size < need_full) return;  // ws measured 256 MB (R2); need ~154 MB

  const ushort* GT = (const ushort*)(ws + OFF_GT);
  const ushort* GI = (const ushort*)(ws + OFF_GI);
  k_mean9 <<<256,  256, 0, stream>>>(fT, ws);
  k_prep9 <<<1024, 256, 0, stream>>>(fT, fI, ws);
  k_gemm9 <<<1024, 256, 0, stream>>>(GT, GI, ws);   // S + colmax partials
  k_pass1 <<<1024, 256, 0, stream>>>(ws);           // Wsum partials
  k_gb9   <<<64,   256, 0, stream>>>(ws);           // gamma/beta arrays
  k_pass2 <<<1024, 256, 0, stream>>>(ws);           // maxv
  k_final9<<<1,    256, 0, stream>>>(ws, out);
}